// Round 2
// baseline (1771.927 us; speedup 1.0000x reference)
//
#include <hip/hip_runtime.h>
#include <math.h>
#include <stdint.h>

// ---------------------------------------------------------------------------
// SNN forward — R9: 2 waves per batch row (neuron-split) for 2x latency
// hiding + R7-proven gather (u16 lists, pad-8, depth-2) + R8 GEMM retile.
//
// Bit-exactness contract (R3..R8, absmax 4.882812e-4):
//   - layer-1: c=0; for d ascending: c=fmaf(w,x,c); then __fadd_rn(c,bias)
//   - spike layers: sum over spiking k ASCENDING, sequential __fadd_rn chain
//     seeded 0; sentinel k=256 hits zeroed row (c+0=c; c never -0)
//   - LIF: individually-rounded fp32 ops, reset from PREVIOUS mem
//   R9 changes only WHICH lane computes each neuron (2/lane across 2 waves
//   instead of 4/lane on 1 wave) and load width (float2/float1). Per-neuron
//   arithmetic chains are identical -> bit-identical results.
//
// R8 post-mortem: depth-4 pipeline collapsed (VGPR 112 << 128 needed for the
// W buffers -> compiler serialized it; VALUBusy 25.7->22.0), pad-32 added
// sentinel gathers, u32 lists added 198K LDS bank conflicts. snn_rec
// 980->1062us. GEMM retile worked (-70us). R9 reverts the gather to R7 form
// and attacks the real limit: Occupancy 11.5% (grid-bound, 4 waves/CU,
// ~75% stall on L2 gather latency). Row split across 2 waves -> 1024 blocks
// x 128 thr -> 8 waves/CU. Full 256-bit spike mask exchanged via LDS with
// 3 rotating buffers + 1 __syncthreads per layer (race-free: a buffer's
// rewrite is separated from its read by two intervening barriers).
// ---------------------------------------------------------------------------

namespace {

constexpr int Bsz = 1024;
constexpr int Dd  = 256;
constexpr int Tt  = 128;
constexpr int Hh  = 256;
constexpr int Oo  = 64;

// Wt[c*R + r] = W[r*C + c] for c<C; row c==C zeroed (sparse sentinel target).
__global__ void pack_t(const float* __restrict__ W, float* __restrict__ Wt,
                       int R, int C) {
    int idx = blockIdx.x * 256 + threadIdx.x;
    if (idx >= (C + 1) * R) return;
    int c = idx / R, r = idx - c * R;
    Wt[idx] = (c < C) ? W[(size_t)r * C + c] : 0.f;
}

// WtO[k*128 + o]: o<64 -> W_f[o][k], o>=64 -> W_a[o-64][k]; row k==256 zeroed.
__global__ void pack_o(const float* __restrict__ Wf, const float* __restrict__ Wa,
                       float* __restrict__ WtO) {
    int idx = blockIdx.x * 256 + threadIdx.x;
    if (idx >= 257 * 128) return;
    int k = idx >> 7, o = idx & 127;
    float v = 0.f;
    if (k < 256) v = (o < 64) ? Wf[(size_t)o * 256 + k] : Wa[(size_t)(o - 64) * 256 + k];
    WtO[idx] = v;
}

__device__ __forceinline__ float clamp01(float v) { return fminf(fmaxf(v, 0.f), 1.f); }

__device__ __forceinline__ bool lif_step(float& m, float cur, float B, float Th) {
    const float r = (__fsub_rn(m, Th) > 0.f) ? Th : 0.f;   // reset from PREVIOUS mem
    m = __fsub_rn(__fadd_rn(__fmul_rn(B, m), cur), r);
    return __fsub_rn(m, Th) > 0.f;
}

// Per-wave local half-mask: wave 'half' owns neurons half*128 + 2L, 2L+1.
// W[j] bit p = spike of neuron half*128 + 64j + p, owner lane 32j+(p>>1),
// bit (p&1) of its 2-bit nib.
__device__ __forceinline__ void make_half_masks(int nib2, int lane, uint64_t* W) {
    #pragma unroll
    for (int j = 0; j < 2; ++j) {
        const int v   = __shfl(nib2, 32 * j + (lane >> 1), 64);
        const int bit = (v >> (lane & 1)) & 1;
        W[j] = __ballot(bit != 0);
    }
}

// Branchless compaction from the full 256-bit mask alone. For list-building
// purposes lane owns neurons 4L..4L+3 (independent of LIF ownership).
// Writes ascending-neuron u16 index list, pads to multiple of 8 with
// sentinel Hh (zeroed table row). Returns npad (uniform).
__device__ __forceinline__ int compact(int lane, const uint64_t* M, uint16_t* lst) {
    const int nib = (int)((M[lane >> 4] >> ((lane & 15) << 2)) & 0xFull);
    const int p0 = (int)__popcll(M[0]);
    const int p1 = (int)__popcll(M[1]);
    const int p2 = (int)__popcll(M[2]);
    const int p3 = (int)__popcll(M[3]);
    const int q  = lane >> 4;
    const int base = ((q >= 1) ? p0 : 0) + ((q >= 2) ? p1 : 0) + ((q >= 3) ? p2 : 0);
    const uint64_t mq = (q & 2) ? ((q & 1) ? M[3] : M[2])
                                : ((q & 1) ? M[1] : M[0]);
    const int posb = (lane & 15) << 2;
    const int r0 = base + (int)__popcll(mq & ((1ull << posb) - 1ull));
    const int s1 = nib & 1;
    const int s2 = s1 + ((nib >> 1) & 1);
    const int s3 = s2 + ((nib >> 2) & 1);
    const int nb = lane << 2;
    if (nib & 1) lst[r0]      = (uint16_t)nb;
    if (nib & 2) lst[r0 + s1] = (uint16_t)(nb + 1);
    if (nib & 4) lst[r0 + s2] = (uint16_t)(nb + 2);
    if (nib & 8) lst[r0 + s3] = (uint16_t)(nb + 3);
    const int n    = p0 + p1 + p2 + p3;
    const int npad = (n + 7) & ~7;
    if (lane < npad - n) lst[n + lane] = (uint16_t)Hh;
    return npad;
}

// ---- hidden-layer gather: 8 dwordx2 loads per batch, depth-2 pipeline -----
// Each wave fetches its 512B half of the 1KB row: offB = half*512 + lane*8.

__device__ __forceinline__ void issue8h(const char* __restrict__ tab,
                                        uint4 I, int offB, float2* w) {
    const uint32_t k[8] = {(I.x & 0xffffu) << 10, (I.x >> 16) << 10,
                           (I.y & 0xffffu) << 10, (I.y >> 16) << 10,
                           (I.z & 0xffffu) << 10, (I.z >> 16) << 10,
                           (I.w & 0xffffu) << 10, (I.w >> 16) << 10};
    #pragma unroll
    for (int i = 0; i < 8; ++i)
        w[i] = *(const float2*)(tab + k[i] + offB);
}

__device__ __forceinline__ void cons8h(float2& c, const float2* w) {
    #pragma unroll
    for (int i = 0; i < 8; ++i) {
        c.x = __fadd_rn(c.x, w[i].x);
        c.y = __fadd_rn(c.y, w[i].y);
    }
}

__device__ __forceinline__ float2 sum_h(const uint16_t* lst, int nbat,
                                        const float* __restrict__ tab, int offB) {
    float2 c = {0.f, 0.f};
    if (nbat == 0) return c;
    const char* tb = (const char*)tab;
    float2 A[8], B[8];
    issue8h(tb, *(const uint4*)(lst), offB, A);
    int i = 1;
    for (; i + 1 < nbat; i += 2) {
        issue8h(tb, *(const uint4*)(lst + 8 * i), offB, B);
        cons8h(c, A);
        issue8h(tb, *(const uint4*)(lst + 8 * (i + 1)), offB, A);
        cons8h(c, B);
    }
    if (i < nbat) {
        issue8h(tb, *(const uint4*)(lst + 8 * i), offB, B);
        cons8h(c, A);
        cons8h(c, B);
    } else {
        cons8h(c, A);
    }
    return c;
}

// ---- output-layer gather: 8 dword loads per batch, depth-2 pipeline -------
// Wave handles 1 output slot per lane: offB = (half*64+lane)*4 in 512B rows.

__device__ __forceinline__ void issue8o(const char* __restrict__ tab,
                                        uint4 I, int offB, float* w) {
    const uint32_t k[8] = {(I.x & 0xffffu) << 9, (I.x >> 16) << 9,
                           (I.y & 0xffffu) << 9, (I.y >> 16) << 9,
                           (I.z & 0xffffu) << 9, (I.z >> 16) << 9,
                           (I.w & 0xffffu) << 9, (I.w >> 16) << 9};
    #pragma unroll
    for (int i = 0; i < 8; ++i)
        w[i] = *(const float*)(tab + k[i] + offB);
}

__device__ __forceinline__ void cons8o(float& c, const float* w) {
    #pragma unroll
    for (int i = 0; i < 8; ++i) c = __fadd_rn(c, w[i]);
}

__device__ __forceinline__ float sum_o(const uint16_t* lst, int nbat,
                                       const float* __restrict__ tab, int offB) {
    float c = 0.f;
    if (nbat == 0) return c;
    const char* tb = (const char*)tab;
    float A[8], B[8];
    issue8o(tb, *(const uint4*)(lst), offB, A);
    int i = 1;
    for (; i + 1 < nbat; i += 2) {
        issue8o(tb, *(const uint4*)(lst + 8 * i), offB, B);
        cons8o(c, A);
        issue8o(tb, *(const uint4*)(lst + 8 * (i + 1)), offB, A);
        cons8o(c, B);
    }
    if (i < nbat) {
        issue8o(tb, *(const uint4*)(lst + 8 * i), offB, B);
        cons8o(c, A);
        cons8o(c, B);
    } else {
        cons8o(c, A);
    }
    return c;
}

// ------------- recurrent kernel: TWO WAVES per batch row -------------------
// 128 threads = 2 waves; wave 'half' owns hidden neurons half*128+2L,+1 and
// output slot half*64+L. Full spike mask exchanged via LDS (3 rotating
// buffers, 1 __syncthreads per layer). 1024 blocks -> 8 waves/CU.
__global__ __launch_bounds__(128, 2) void snn_rec(
    const float* __restrict__ cur1,     // [b][t_local][h]
    const float* __restrict__ Wt_h, const float* __restrict__ Wt_h1,
    const float* __restrict__ WtO,
    const float* __restrict__ beta1, const float* __restrict__ thr1,
    const float* __restrict__ b_h,  const float* __restrict__ beta2, const float* __restrict__ thr2,
    const float* __restrict__ b_h1,
    const float* __restrict__ b_f,  const float* __restrict__ beta_f,
    const float* __restrict__ b_a,  const float* __restrict__ beta_a,
    float* __restrict__ m1s, float* __restrict__ m2s, float* __restrict__ m3s,
    float* __restrict__ mos, float* __restrict__ out,
    int TC, int first)
{
    __shared__ __attribute__((aligned(16))) uint16_t lists[2][272];
    __shared__ uint64_t mbuf[3][2][2];   // [layer][half][word]

    const int tid  = threadIdx.x;
    const int lane = tid & 63;
    const int half = tid >> 6;            // wave id within row
    const int b    = blockIdx.x;
    uint16_t* lst  = lists[half];
    const int hbase = half * 128 + lane * 2;   // 2 hidden neurons per lane
    const int offBh = half * 512 + lane * 8;   // byte offset into 1KB rows
    const int oslot = half * 64 + lane;        // 1 output slot per lane
    const int offBo = oslot * 4;               // byte offset into 512B rows

    const float2 B1v  = *(const float2*)(beta1 + hbase);
    const float2 Th1v = *(const float2*)(thr1  + hbase);
    const float2 bhv  = *(const float2*)(b_h   + hbase);
    const float2 B2v  = *(const float2*)(beta2 + hbase);
    const float2 Th2v = *(const float2*)(thr2  + hbase);
    const float2 bh1v = *(const float2*)(b_h1  + hbase);
    const float2 B1c  = {clamp01(B1v.x), clamp01(B1v.y)};
    const float2 B2c  = {clamp01(B2v.x), clamp01(B2v.y)};

    const float* bop = half ? b_a    : b_f;    // half0 -> mf, half1 -> ma
    const float* Bop = half ? beta_a : beta_f;
    const float bo = bop[lane];
    const float Bo = clamp01(Bop[lane]);

    float2 m1, m2, m3;
    float mo;
    if (first) {
        m1 = m2 = m3 = make_float2(0.f, 0.f);
        mo = 0.f;
    } else {
        m1 = *(const float2*)(m1s + (size_t)b * Hh + hbase);
        m2 = *(const float2*)(m2s + (size_t)b * Hh + hbase);
        m3 = *(const float2*)(m3s + (size_t)b * Hh + hbase);
        mo = mos[(size_t)b * 128 + oslot];
    }

    const float* __restrict__ curb = cur1 + (size_t)b * TC * Hh + hbase;
    float2 cur = *(const float2*)(curb);
    uint64_t M[4], W01[2];

    for (int t = 0; t < TC; ++t) {
        // ---- layer 1 (cur precomputed by GEMM, bias included) -------------
        int nib2 = 0;
        nib2 |= (int)lif_step(m1.x, cur.x, B1c.x, Th1v.x);
        nib2 |= (int)lif_step(m1.y, cur.y, B1c.y, Th1v.y) << 1;
        float2 curN;
        if (t + 1 < TC) curN = *(const float2*)(curb + (size_t)(t + 1) * Hh);  // prefetch
        make_half_masks(nib2, lane, W01);
        if (lane == 0) { mbuf[0][half][0] = W01[0]; mbuf[0][half][1] = W01[1]; }
        __syncthreads();
        M[0] = mbuf[0][0][0]; M[1] = mbuf[0][0][1];
        M[2] = mbuf[0][1][0]; M[3] = mbuf[0][1][1];
        int npad = compact(lane, M, lst);

        // ---- layer 2 ------------------------------------------------------
        float2 s = sum_h(lst, npad >> 3, Wt_h, offBh);
        nib2  = (int)lif_step(m2.x, __fadd_rn(s.x, bhv.x), B2c.x, Th2v.x);
        nib2 |= (int)lif_step(m2.y, __fadd_rn(s.y, bhv.y), B2c.y, Th2v.y) << 1;
        make_half_masks(nib2, lane, W01);
        if (lane == 0) { mbuf[1][half][0] = W01[0]; mbuf[1][half][1] = W01[1]; }
        __syncthreads();
        M[0] = mbuf[1][0][0]; M[1] = mbuf[1][0][1];
        M[2] = mbuf[1][1][0]; M[3] = mbuf[1][1][1];
        npad = compact(lane, M, lst);

        // ---- layer 3 (reuses beta2/thr2 — source bug preserved) ----------
        s = sum_h(lst, npad >> 3, Wt_h1, offBh);
        nib2  = (int)lif_step(m3.x, __fadd_rn(s.x, bh1v.x), B2c.x, Th2v.x);
        nib2 |= (int)lif_step(m3.y, __fadd_rn(s.y, bh1v.y), B2c.y, Th2v.y) << 1;
        make_half_masks(nib2, lane, W01);
        if (lane == 0) { mbuf[2][half][0] = W01[0]; mbuf[2][half][1] = W01[1]; }
        __syncthreads();
        M[0] = mbuf[2][0][0]; M[1] = mbuf[2][0][1];
        M[2] = mbuf[2][1][0]; M[3] = mbuf[2][1][1];
        npad = compact(lane, M, lst);

        // ---- output LI neurons (no reset) --------------------------------
        const float os = sum_o(lst, npad >> 3, WtO, offBo);
        mo = __fadd_rn(__fmul_rn(Bo, mo), __fadd_rn(os, bo));
        cur = curN;
    }

    *(float2*)(m1s + (size_t)b * Hh + hbase) = m1;
    *(float2*)(m2s + (size_t)b * Hh + hbase) = m2;
    *(float2*)(m3s + (size_t)b * Hh + hbase) = m3;
    mos[(size_t)b * 128 + oslot] = mo;

    float* dst = out + (size_t)half * Bsz * Oo + (size_t)b * Oo + lane;
    *dst = (float)(1.0 / (1.0 + exp(-(double)mo)));
}

// ---------------- layer-1 GEMM, register-tiled 4h x 8t per thread ----------
// Block: 256 threads = 64 h-quads x 4 t-groups; TT=32 t-columns per block.
// Per d: 1 float4 w-load (coalesced 1KB/wave) + 2 ds_read_b128 -> 32 fma.
// Bit-exact: per (h,t) c is a sequential fmaf chain over d ascending.
template<int TT>
__global__ __launch_bounds__(256) void gemm_l1_r8(
    const float* __restrict__ x, const float* __restrict__ Wt_in,
    const float* __restrict__ b_in, float* __restrict__ cur1,
    int tg_base, int TCloc)
{
    __shared__ float xs[Dd][TT];
    const int tid = threadIdx.x;
    const int b   = blockIdx.x;
    const int ty  = blockIdx.y;
    const int tg0 = tg_base + ty * TT;
    const float* xb = x + (size_t)b * Dd * Tt + tg0;
    constexpr int T4 = TT / 4;
    for (int v = tid; v < Dd * T4; v += 256) {
        const int d = v / T4, j4 = v - d * T4;
        *(float4*)&xs[d][j4 * 4] = *(const float4*)(xb + (size_t)d * Tt + j4 * 4);
    }
    __syncthreads();
    constexpr int TS = TT / 4;          // 8 t per thread
    const int hq = tid & 63;            // h base = 4*hq
    const int tq = tid >> 6;            // t base = TS*tq
    float c0[TS], c1[TS], c2[TS], c3[TS];
    #pragma unroll
    for (int j = 0; j < TS; ++j) { c0[j] = 0.f; c1[j] = 0.f; c2[j] = 0.f; c3[j] = 0.f; }
    const float* wp = Wt_in + hq * 4;
    #pragma unroll 4
    for (int d = 0; d < Dd; ++d) {
        const float4 w = *(const float4*)(wp + (size_t)d * Hh);
        #pragma unroll
        for (int j = 0; j < TS; ++j) {
            const float xv = xs[d][tq * TS + j];
            c0[j] = fmaf(w.x, xv, c0[j]);
            c1[j] = fmaf(w.y, xv, c1[j]);
            c2[j] = fmaf(w.z, xv, c2[j]);
            c3[j] = fmaf(w.w, xv, c3[j]);
        }
    }
    const float4 bb = *(const float4*)(b_in + hq * 4);
    float* cb = cur1 + ((size_t)b * TCloc + ty * TT + tq * TS) * Hh + hq * 4;
    #pragma unroll
    for (int j = 0; j < TS; ++j) {
        float4 o;
        o.x = __fadd_rn(c0[j], bb.x);
        o.y = __fadd_rn(c1[j], bb.y);
        o.z = __fadd_rn(c2[j], bb.z);
        o.w = __fadd_rn(c3[j], bb.w);
        *(float4*)(cb + (size_t)j * Hh) = o;
    }
}

// ---- small-TC fallbacks (unchanged) ---------------------------------------
template<int TT>
__global__ __launch_bounds__(256) void gemm_l1_lds(
    const float* __restrict__ x, const float* __restrict__ Wt_in,
    const float* __restrict__ b_in, float* __restrict__ cur1,
    int tg_base, int TCloc)
{
    __shared__ float xs[Dd][TT];
    const int h   = threadIdx.x;
    const int b   = blockIdx.x;
    const int ty  = blockIdx.y;
    const int tg0 = tg_base + ty * TT;
    const float* xb = x + (size_t)b * Dd * Tt + tg0;
    constexpr int T4 = TT / 4;
    for (int v = threadIdx.x; v < Dd * T4; v += 256) {
        const int d = v / T4, j4 = v - d * T4;
        *(float4*)&xs[d][j4 * 4] = *(const float4*)(xb + (size_t)d * Tt + j4 * 4);
    }
    __syncthreads();
    float c[TT];
    #pragma unroll
    for (int j = 0; j < TT; ++j) c[j] = 0.f;
    for (int d = 0; d < Dd; ++d) {
        const float w = Wt_in[d * Hh + h];        // coalesced
        #pragma unroll
        for (int j = 0; j < TT; ++j) c[j] = fmaf(w, xs[d][j], c[j]);  // broadcast
    }
    const float bb = b_in[h];
    float* cb = cur1 + ((size_t)b * TCloc + ty * TT) * Hh;
    #pragma unroll
    for (int j = 0; j < TT; ++j) cb[j * Hh + h] = __fadd_rn(c[j], bb);
}

template<int TT>
__global__ __launch_bounds__(256) void gemm_l1_simple(
    const float* __restrict__ x, const float* __restrict__ Wt_in,
    const float* __restrict__ b_in, float* __restrict__ cur1, int tg0)
{
    const int h = threadIdx.x;
    const int b = blockIdx.x;
    float c[TT];
    #pragma unroll
    for (int j = 0; j < TT; ++j) c[j] = 0.f;
    const float* xb = x + (size_t)b * Dd * Tt + tg0;
    for (int d = 0; d < Dd; ++d) {
        const float w = Wt_in[d * Hh + h];
        const float* xp = xb + (size_t)d * Tt;
        #pragma unroll
        for (int j = 0; j < TT; ++j) c[j] = fmaf(w, xp[j], c[j]);
    }
    const float bb = b_in[h];
    float* cb = cur1 + (size_t)b * TT * Hh;
    #pragma unroll
    for (int j = 0; j < TT; ++j) cb[j * Hh + h] = __fadd_rn(c[j], bb);
}

} // namespace

extern "C" void kernel_launch(void* const* d_in, const int* in_sizes, int n_in,
                              void* d_out, int out_size, void* d_ws, size_t ws_size,
                              hipStream_t stream) {
    const float* x      = (const float*)d_in[0];
    const float* W_in   = (const float*)d_in[1];
    const float* b_in   = (const float*)d_in[2];
    const float* beta1  = (const float*)d_in[3];
    const float* thr1   = (const float*)d_in[4];
    const float* W_h    = (const float*)d_in[5];
    const float* b_h    = (const float*)d_in[6];
    const float* beta2  = (const float*)d_in[7];
    const float* thr2   = (const float*)d_in[8];
    const float* W_h1   = (const float*)d_in[9];
    const float* b_h1   = (const float*)d_in[10];
    const float* W_f    = (const float*)d_in[11];
    const float* b_f    = (const float*)d_in[12];
    const float* beta_f = (const float*)d_in[13];
    const float* W_a    = (const float*)d_in[14];
    const float* b_a    = (const float*)d_in[15];
    const float* beta_a = (const float*)d_in[16];
    float* out = (float*)d_out;

    float* ws = (float*)d_ws;
    size_t off = 0;
    auto alloc = [&](size_t n) { float* p = ws + off; off += n; return p; };
    float* Wt_in = alloc(257 * 256);
    float* Wt_h  = alloc(257 * 256);
    float* Wt_h1 = alloc(257 * 256);
    float* WtO   = alloc(257 * 128);
    float* m1s   = alloc((size_t)Bsz * Hh);
    float* m2s   = alloc((size_t)Bsz * Hh);
    float* m3s   = alloc((size_t)Bsz * Hh);
    float* mos   = alloc((size_t)Bsz * 128);
    const size_t fixed = off;

    int TC = 1;
    const int cands[8] = {128, 64, 32, 16, 8, 4, 2, 1};
    for (int i = 0; i < 8; ++i) {
        if ((fixed + (size_t)cands[i] * Bsz * Hh) * sizeof(float) <= ws_size) { TC = cands[i]; break; }
    }
    float* cur1 = alloc((size_t)TC * Bsz * Hh);

    pack_t<<<257, 256, 0, stream>>>(W_in, Wt_in, 256, 256);
    pack_t<<<257, 256, 0, stream>>>(W_h,  Wt_h,  256, 256);
    pack_t<<<257, 256, 0, stream>>>(W_h1, Wt_h1, 256, 256);
    pack_o<<<129, 256, 0, stream>>>(W_f, W_a, WtO);

    const int nch = Tt / TC;
    for (int c = 0; c < nch; ++c) {
        const int tg = c * TC;
        if (TC >= 32)
            gemm_l1_r8<32><<<dim3(Bsz, TC / 32), 256, 0, stream>>>(x, Wt_in, b_in, cur1, tg, TC);
        else if (TC == 16)
            gemm_l1_lds<16><<<dim3(Bsz, 1), 256, 0, stream>>>(x, Wt_in, b_in, cur1, tg, TC);
        else if (TC == 8)
            gemm_l1_lds<8><<<dim3(Bsz, 1), 256, 0, stream>>>(x, Wt_in, b_in, cur1, tg, TC);
        else if (TC == 4)
            gemm_l1_simple<4><<<Bsz, 256, 0, stream>>>(x, Wt_in, b_in, cur1, tg);
        else if (TC == 2)
            gemm_l1_simple<2><<<Bsz, 256, 0, stream>>>(x, Wt_in, b_in, cur1, tg);
        else
            gemm_l1_simple<1><<<Bsz, 256, 0, stream>>>(x, Wt_in, b_in, cur1, tg);

        snn_rec<<<Bsz, 128, 0, stream>>>(
            cur1, Wt_h, Wt_h1, WtO,
            beta1, thr1, b_h, beta2, thr2, b_h1,
            b_f, beta_f, b_a, beta_a,
            m1s, m2s, m3s, mos, out, TC, (c == 0) ? 1 : 0);
    }
}

// Round 3
// 1128.996 us; speedup vs baseline: 1.5695x; 1.5695x over previous
//
#include <hip/hip_runtime.h>
#include <math.h>
#include <stdint.h>

// ---------------------------------------------------------------------------
// SNN forward — R10: R7 wave-per-row structure restored + WtO staged in LDS
// (128.5 KB) + sched_barrier-pinned depth-3 sum_h pipeline + R8 GEMM retile.
//
// Bit-exactness contract (R3..R9, absmax 4.882812e-4):
//   - layer-1: c=0; for d ascending: c=fmaf(w,x,c); then __fadd_rn(c,bias)
//   - spike layers: sum over spiking k ASCENDING, sequential __fadd_rn chain
//     seeded 0; sentinel k=256 hits zeroed row (c+0=c; c never -0)
//   - LIF: individually-rounded fp32 ops, reset from PREVIOUS mem
//
// R9 post-mortem: row-split across 2 waves doubled load issue without
// shortening the per-row serial chain (8 loads/batch either way) and added
// 3 barriers/step -> 1062->1513us. Reverted. R10 levers shorten the chain:
// (a) sum_o gathers from LDS-resident WtO (ds_read ~60cy vs L2 ~400cy;
//     2-way bank aliasing = free), values bit-identical;
// (b) sum_h depth-3 (24 outstanding loads), pinned with
//     __builtin_amdgcn_sched_barrier(0) after each issue group so the
//     scheduler cannot collapse the rotation (R8's failure mode).
// Consume order remains ascending-batch, ascending-entry everywhere.
// ---------------------------------------------------------------------------

namespace {

constexpr int Bsz = 1024;
constexpr int Dd  = 256;
constexpr int Tt  = 128;
constexpr int Hh  = 256;
constexpr int Oo  = 64;

// Wt[c*R + r] = W[r*C + c] for c<C; row c==C zeroed (sparse sentinel target).
__global__ void pack_t(const float* __restrict__ W, float* __restrict__ Wt,
                       int R, int C) {
    int idx = blockIdx.x * 256 + threadIdx.x;
    if (idx >= (C + 1) * R) return;
    int c = idx / R, r = idx - c * R;
    Wt[idx] = (c < C) ? W[(size_t)r * C + c] : 0.f;
}

// WtO[k*128 + o]: o<64 -> W_f[o][k], o>=64 -> W_a[o-64][k]; row k==256 zeroed.
__global__ void pack_o(const float* __restrict__ Wf, const float* __restrict__ Wa,
                       float* __restrict__ WtO) {
    int idx = blockIdx.x * 256 + threadIdx.x;
    if (idx >= 257 * 128) return;
    int k = idx >> 7, o = idx & 127;
    float v = 0.f;
    if (k < 256) v = (o < 64) ? Wf[(size_t)o * 256 + k] : Wa[(size_t)(o - 64) * 256 + k];
    WtO[idx] = v;
}

__device__ __forceinline__ float clamp01(float v) { return fminf(fmaxf(v, 0.f), 1.f); }

__device__ __forceinline__ bool lif_step(float& m, float cur, float B, float Th) {
    const float r = (__fsub_rn(m, Th) > 0.f) ? Th : 0.f;   // reset from PREVIOUS mem
    m = __fsub_rn(__fadd_rn(__fmul_rn(B, m), cur), r);
    return __fsub_rn(m, Th) > 0.f;
}

// Build 256-bit spike mask from 4 bits/lane (lane owns neurons 4L..4L+3):
// word q bit p = neuron 64q+p, contributed by lane 16q+(p>>2), bit (p&3).
__device__ __forceinline__ void make_masks(int nib, int lane, uint64_t* M) {
    #pragma unroll
    for (int q = 0; q < 4; ++q) {
        const int v   = __shfl(nib, 16 * q + (lane >> 2), 64);
        const int bit = (v >> (lane & 3)) & 1;
        M[q] = __ballot(bit != 0);
    }
}

// Branchless compaction: write ascending-neuron u16 index list to lst,
// pad to multiple of 8 with sentinel Hh. Returns npad (uniform).
__device__ __forceinline__ int compact(int nib, int lane, const uint64_t* M,
                                       uint16_t* lst) {
    const int p0 = (int)__popcll(M[0]);
    const int p1 = (int)__popcll(M[1]);
    const int p2 = (int)__popcll(M[2]);
    const int p3 = (int)__popcll(M[3]);
    const int q  = lane >> 4;
    const int base = ((q >= 1) ? p0 : 0) + ((q >= 2) ? p1 : 0) + ((q >= 3) ? p2 : 0);
    const uint64_t mq = (q & 2) ? ((q & 1) ? M[3] : M[2])
                                : ((q & 1) ? M[1] : M[0]);
    const int posb = (lane & 15) << 2;
    const int r0 = base + (int)__popcll(mq & ((1ull << posb) - 1ull));
    const int s1 = nib & 1;
    const int s2 = s1 + ((nib >> 1) & 1);
    const int s3 = s2 + ((nib >> 2) & 1);
    const int nb = lane << 2;
    if (nib & 1) lst[r0]      = (uint16_t)nb;
    if (nib & 2) lst[r0 + s1] = (uint16_t)(nb + 1);
    if (nib & 4) lst[r0 + s2] = (uint16_t)(nb + 2);
    if (nib & 8) lst[r0 + s3] = (uint16_t)(nb + 3);
    const int n    = p0 + p1 + p2 + p3;
    const int npad = (n + 7) & ~7;
    if (lane < npad - n) lst[n + lane] = (uint16_t)Hh;
    return npad;
}

// ---- hidden-layer gather: 8 dwordx4 loads per batch, depth-3 pipeline -----

__device__ __forceinline__ void issue8h(const char* __restrict__ tab,
                                        uint4 I, int offB, float4* w) {
    const int k[8] = {(int)(I.x & 0xffff), (int)(I.x >> 16),
                      (int)(I.y & 0xffff), (int)(I.y >> 16),
                      (int)(I.z & 0xffff), (int)(I.z >> 16),
                      (int)(I.w & 0xffff), (int)(I.w >> 16)};
    #pragma unroll
    for (int i = 0; i < 8; ++i)
        w[i] = *(const float4*)(tab + (k[i] << 10) + offB);
}

__device__ __forceinline__ void cons8h(float4& c, const float4* w) {
    #pragma unroll
    for (int i = 0; i < 8; ++i) {
        c.x = __fadd_rn(c.x, w[i].x);
        c.y = __fadd_rn(c.y, w[i].y);
        c.z = __fadd_rn(c.z, w[i].z);
        c.w = __fadd_rn(c.w, w[i].w);
    }
}

// Depth-3 rotation, consume order ascending (bit-exact). sched_barrier(0)
// after each issue group pins the rotation against scheduler collapse (R8).
__device__ __forceinline__ float4 sum_h(const uint16_t* lst, int nbat,
                                        const float* __restrict__ tab, int offB) {
    float4 c = {0.f, 0.f, 0.f, 0.f};
    if (nbat == 0) return c;
    const char* tb = (const char*)tab;
    float4 A[8], B[8], C[8];
    issue8h(tb, *(const uint4*)(lst), offB, A);
    if (nbat == 1) { cons8h(c, A); return c; }
    issue8h(tb, *(const uint4*)(lst + 8), offB, B);
    if (nbat == 2) { cons8h(c, A); cons8h(c, B); return c; }
    issue8h(tb, *(const uint4*)(lst + 16), offB, C);
    __builtin_amdgcn_sched_barrier(0);
    int i = 3;
    for (; i + 2 < nbat; i += 3) {
        cons8h(c, A); issue8h(tb, *(const uint4*)(lst + 8 * i), offB, A);
        __builtin_amdgcn_sched_barrier(0);
        cons8h(c, B); issue8h(tb, *(const uint4*)(lst + 8 * (i + 1)), offB, B);
        __builtin_amdgcn_sched_barrier(0);
        cons8h(c, C); issue8h(tb, *(const uint4*)(lst + 8 * (i + 2)), offB, C);
        __builtin_amdgcn_sched_barrier(0);
    }
    const int r = nbat - i;
    if (r == 0) {
        cons8h(c, A); cons8h(c, B); cons8h(c, C);
    } else if (r == 1) {
        cons8h(c, A); issue8h(tb, *(const uint4*)(lst + 8 * i), offB, A);
        cons8h(c, B); cons8h(c, C); cons8h(c, A);
    } else {
        cons8h(c, A); issue8h(tb, *(const uint4*)(lst + 8 * i), offB, A);
        cons8h(c, B); issue8h(tb, *(const uint4*)(lst + 8 * (i + 1)), offB, B);
        cons8h(c, C); cons8h(c, A); cons8h(c, B);
    }
    return c;
}

// ---- output-layer gather from LDS-resident WtO (ds_read_b64, ~free banks) -

__device__ __forceinline__ float2 sum_o_lds(const uint16_t* lst, int nbat,
                                            const float* tab, int offB) {
    float2 c = {0.f, 0.f};
    const char* tb = (const char*)tab;
    for (int i = 0; i < nbat; ++i) {
        const uint4 I = *(const uint4*)(lst + 8 * i);
        float2 w[8];
        w[0] = *(const float2*)(tb + ((I.x & 0xffffu) << 9) + offB);
        w[1] = *(const float2*)(tb + ((I.x >> 16)    << 9) + offB);
        w[2] = *(const float2*)(tb + ((I.y & 0xffffu) << 9) + offB);
        w[3] = *(const float2*)(tb + ((I.y >> 16)    << 9) + offB);
        w[4] = *(const float2*)(tb + ((I.z & 0xffffu) << 9) + offB);
        w[5] = *(const float2*)(tb + ((I.z >> 16)    << 9) + offB);
        w[6] = *(const float2*)(tb + ((I.w & 0xffffu) << 9) + offB);
        w[7] = *(const float2*)(tb + ((I.w >> 16)    << 9) + offB);
        #pragma unroll
        for (int j = 0; j < 8; ++j) {
            c.x = __fadd_rn(c.x, w[j].x);
            c.y = __fadd_rn(c.y, w[j].y);
        }
    }
    return c;
}

// ---------------- recurrent kernel: one WAVE per batch row -----------------
// 256 threads = 4 independent waves, per-wave LDS lists; the only barrier is
// the one-time WtO staging sync before the t-loop.
__global__ __launch_bounds__(256, 1) void snn_rec(
    const float* __restrict__ cur1,     // [b][t_local][h]
    const float* __restrict__ Wt_h, const float* __restrict__ Wt_h1,
    const float* __restrict__ WtO,
    const float* __restrict__ beta1, const float* __restrict__ thr1,
    const float* __restrict__ b_h,  const float* __restrict__ beta2, const float* __restrict__ thr2,
    const float* __restrict__ b_h1,
    const float* __restrict__ b_f,  const float* __restrict__ beta_f,
    const float* __restrict__ b_a,  const float* __restrict__ beta_a,
    float* __restrict__ m1s, float* __restrict__ m2s, float* __restrict__ m3s,
    float* __restrict__ mos, float* __restrict__ out,
    int TC, int first)
{
    __shared__ __attribute__((aligned(16))) float ldsO[257 * 128];   // 128.5 KB
    __shared__ __attribute__((aligned(16))) uint16_t lists[4][272];

    const int tid  = threadIdx.x;
    const int lane = tid & 63;
    const int b    = blockIdx.x * 4 + (tid >> 6);
    uint16_t* lst  = lists[tid >> 6];
    const int off4 = lane * 4;          // hidden neuron base 4L
    const int off2 = lane * 2;          // output slot base 2L
    const int offBh = lane * 16;        // byte offset into 1KB hidden rows
    const int offBo = lane * 8;         // byte offset into 512B output rows

    // ---- stage WtO into LDS (one-time; bit-identical values) --------------
    {
        const float4* s4 = (const float4*)WtO;
        float4* d4 = (float4*)ldsO;
        for (int v = tid; v < (257 * 128) / 4; v += 256) d4[v] = s4[v];
    }
    __syncthreads();

    const float4 B1v  = *(const float4*)(beta1 + off4);
    const float4 Th1v = *(const float4*)(thr1  + off4);
    const float4 bhv  = *(const float4*)(b_h   + off4);
    const float4 B2v  = *(const float4*)(beta2 + off4);
    const float4 Th2v = *(const float4*)(thr2  + off4);
    const float4 bh1v = *(const float4*)(b_h1  + off4);
    const float4 B1c  = {clamp01(B1v.x), clamp01(B1v.y), clamp01(B1v.z), clamp01(B1v.w)};
    const float4 B2c  = {clamp01(B2v.x), clamp01(B2v.y), clamp01(B2v.z), clamp01(B2v.w)};

    const int oo = off2 & 63;
    const float* bop = (lane < 32) ? b_f    : b_a;
    const float* Bop = (lane < 32) ? beta_f : beta_a;
    const float bo0 = bop[oo], bo1 = bop[oo + 1];
    const float Bo0 = clamp01(Bop[oo]), Bo1 = clamp01(Bop[oo + 1]);

    float4 m1, m2, m3;
    float mo0, mo1;
    if (first) {
        m1 = m2 = m3 = make_float4(0.f, 0.f, 0.f, 0.f);
        mo0 = mo1 = 0.f;
    } else {
        m1 = *(const float4*)(m1s + (size_t)b * Hh + off4);
        m2 = *(const float4*)(m2s + (size_t)b * Hh + off4);
        m3 = *(const float4*)(m3s + (size_t)b * Hh + off4);
        const float2 mo = *(const float2*)(mos + (size_t)b * 128 + off2);
        mo0 = mo.x; mo1 = mo.y;
    }

    const float* __restrict__ curb = cur1 + (size_t)b * TC * Hh + off4;
    float4 cur = *(const float4*)(curb);
    uint64_t M[4];

    for (int t = 0; t < TC; ++t) {
        // ---- layer 1 (cur precomputed by GEMM, bias included) -------------
        int nib = 0;
        nib |= (int)lif_step(m1.x, cur.x, B1c.x, Th1v.x);
        nib |= (int)lif_step(m1.y, cur.y, B1c.y, Th1v.y) << 1;
        nib |= (int)lif_step(m1.z, cur.z, B1c.z, Th1v.z) << 2;
        nib |= (int)lif_step(m1.w, cur.w, B1c.w, Th1v.w) << 3;
        make_masks(nib, lane, M);
        int npad = compact(nib, lane, M, lst);
        if (t + 1 < TC) cur = *(const float4*)(curb + (size_t)(t + 1) * Hh);  // prefetch

        // ---- layer 2 ------------------------------------------------------
        float4 s = sum_h(lst, npad >> 3, Wt_h, offBh);
        nib  = (int)lif_step(m2.x, __fadd_rn(s.x, bhv.x), B2c.x, Th2v.x);
        nib |= (int)lif_step(m2.y, __fadd_rn(s.y, bhv.y), B2c.y, Th2v.y) << 1;
        nib |= (int)lif_step(m2.z, __fadd_rn(s.z, bhv.z), B2c.z, Th2v.z) << 2;
        nib |= (int)lif_step(m2.w, __fadd_rn(s.w, bhv.w), B2c.w, Th2v.w) << 3;
        make_masks(nib, lane, M);
        npad = compact(nib, lane, M, lst);

        // ---- layer 3 (reuses beta2/thr2 — source bug preserved) ----------
        s = sum_h(lst, npad >> 3, Wt_h1, offBh);
        nib  = (int)lif_step(m3.x, __fadd_rn(s.x, bh1v.x), B2c.x, Th2v.x);
        nib |= (int)lif_step(m3.y, __fadd_rn(s.y, bh1v.y), B2c.y, Th2v.y) << 1;
        nib |= (int)lif_step(m3.z, __fadd_rn(s.z, bh1v.z), B2c.z, Th2v.z) << 2;
        nib |= (int)lif_step(m3.w, __fadd_rn(s.w, bh1v.w), B2c.w, Th2v.w) << 3;
        make_masks(nib, lane, M);
        npad = compact(nib, lane, M, lst);

        // ---- output LI neurons (no reset), gather from LDS ---------------
        const float2 os = sum_o_lds(lst, npad >> 3, ldsO, offBo);
        mo0 = __fadd_rn(__fmul_rn(Bo0, mo0), __fadd_rn(os.x, bo0));
        mo1 = __fadd_rn(__fmul_rn(Bo1, mo1), __fadd_rn(os.y, bo1));
    }

    *(float4*)(m1s + (size_t)b * Hh + off4) = m1;
    *(float4*)(m2s + (size_t)b * Hh + off4) = m2;
    *(float4*)(m3s + (size_t)b * Hh + off4) = m3;
    *(float2*)(mos + (size_t)b * 128 + off2) = make_float2(mo0, mo1);

    float* dst = out + ((lane < 32) ? 0 : (size_t)Bsz * Oo) + (size_t)b * Oo + oo;
    const float o0 = (float)(1.0 / (1.0 + exp(-(double)mo0)));
    const float o1 = (float)(1.0 / (1.0 + exp(-(double)mo1)));
    *(float2*)dst = make_float2(o0, o1);
}

// ---------------- layer-1 GEMM, register-tiled 4h x 8t per thread ----------
// Block: 256 threads = 64 h-quads x 4 t-groups; TT=32 t-columns per block.
// Per d: 1 float4 w-load (coalesced 1KB/wave) + 2 ds_read_b128 -> 32 fma.
// Bit-exact: per (h,t) c is a sequential fmaf chain over d ascending.
template<int TT>
__global__ __launch_bounds__(256) void gemm_l1_r8(
    const float* __restrict__ x, const float* __restrict__ Wt_in,
    const float* __restrict__ b_in, float* __restrict__ cur1,
    int tg_base, int TCloc)
{
    __shared__ float xs[Dd][TT];
    const int tid = threadIdx.x;
    const int b   = blockIdx.x;
    const int ty  = blockIdx.y;
    const int tg0 = tg_base + ty * TT;
    const float* xb = x + (size_t)b * Dd * Tt + tg0;
    constexpr int T4 = TT / 4;
    for (int v = tid; v < Dd * T4; v += 256) {
        const int d = v / T4, j4 = v - d * T4;
        *(float4*)&xs[d][j4 * 4] = *(const float4*)(xb + (size_t)d * Tt + j4 * 4);
    }
    __syncthreads();
    constexpr int TS = TT / 4;          // 8 t per thread
    const int hq = tid & 63;            // h base = 4*hq
    const int tq = tid >> 6;            // t base = TS*tq
    float c0[TS], c1[TS], c2[TS], c3[TS];
    #pragma unroll
    for (int j = 0; j < TS; ++j) { c0[j] = 0.f; c1[j] = 0.f; c2[j] = 0.f; c3[j] = 0.f; }
    const float* wp = Wt_in + hq * 4;
    #pragma unroll 4
    for (int d = 0; d < Dd; ++d) {
        const float4 w = *(const float4*)(wp + (size_t)d * Hh);
        #pragma unroll
        for (int j = 0; j < TS; ++j) {
            const float xv = xs[d][tq * TS + j];
            c0[j] = fmaf(w.x, xv, c0[j]);
            c1[j] = fmaf(w.y, xv, c1[j]);
            c2[j] = fmaf(w.z, xv, c2[j]);
            c3[j] = fmaf(w.w, xv, c3[j]);
        }
    }
    const float4 bb = *(const float4*)(b_in + hq * 4);
    float* cb = cur1 + ((size_t)b * TCloc + ty * TT + tq * TS) * Hh + hq * 4;
    #pragma unroll
    for (int j = 0; j < TS; ++j) {
        float4 o;
        o.x = __fadd_rn(c0[j], bb.x);
        o.y = __fadd_rn(c1[j], bb.y);
        o.z = __fadd_rn(c2[j], bb.z);
        o.w = __fadd_rn(c3[j], bb.w);
        *(float4*)(cb + (size_t)j * Hh) = o;
    }
}

// ---- small-TC fallbacks (unchanged) ---------------------------------------
template<int TT>
__global__ __launch_bounds__(256) void gemm_l1_lds(
    const float* __restrict__ x, const float* __restrict__ Wt_in,
    const float* __restrict__ b_in, float* __restrict__ cur1,
    int tg_base, int TCloc)
{
    __shared__ float xs[Dd][TT];
    const int h   = threadIdx.x;
    const int b   = blockIdx.x;
    const int ty  = blockIdx.y;
    const int tg0 = tg_base + ty * TT;
    const float* xb = x + (size_t)b * Dd * Tt + tg0;
    constexpr int T4 = TT / 4;
    for (int v = threadIdx.x; v < Dd * T4; v += 256) {
        const int d = v / T4, j4 = v - d * T4;
        *(float4*)&xs[d][j4 * 4] = *(const float4*)(xb + (size_t)d * Tt + j4 * 4);
    }
    __syncthreads();
    float c[TT];
    #pragma unroll
    for (int j = 0; j < TT; ++j) c[j] = 0.f;
    for (int d = 0; d < Dd; ++d) {
        const float w = Wt_in[d * Hh + h];        // coalesced
        #pragma unroll
        for (int j = 0; j < TT; ++j) c[j] = fmaf(w, xs[d][j], c[j]);  // broadcast
    }
    const float bb = b_in[h];
    float* cb = cur1 + ((size_t)b * TCloc + ty * TT) * Hh;
    #pragma unroll
    for (int j = 0; j < TT; ++j) cb[j * Hh + h] = __fadd_rn(c[j], bb);
}

template<int TT>
__global__ __launch_bounds__(256) void gemm_l1_simple(
    const float* __restrict__ x, const float* __restrict__ Wt_in,
    const float* __restrict__ b_in, float* __restrict__ cur1, int tg0)
{
    const int h = threadIdx.x;
    const int b = blockIdx.x;
    float c[TT];
    #pragma unroll
    for (int j = 0; j < TT; ++j) c[j] = 0.f;
    const float* xb = x + (size_t)b * Dd * Tt + tg0;
    for (int d = 0; d < Dd; ++d) {
        const float w = Wt_in[d * Hh + h];
        const float* xp = xb + (size_t)d * Tt;
        #pragma unroll
        for (int j = 0; j < TT; ++j) c[j] = fmaf(w, xp[j], c[j]);
    }
    const float bb = b_in[h];
    float* cb = cur1 + (size_t)b * TT * Hh;
    #pragma unroll
    for (int j = 0; j < TT; ++j) cb[j * Hh + h] = __fadd_rn(c[j], bb);
}

} // namespace

extern "C" void kernel_launch(void* const* d_in, const int* in_sizes, int n_in,
                              void* d_out, int out_size, void* d_ws, size_t ws_size,
                              hipStream_t stream) {
    const float* x      = (const float*)d_in[0];
    const float* W_in   = (const float*)d_in[1];
    const float* b_in   = (const float*)d_in[2];
    const float* beta1  = (const float*)d_in[3];
    const float* thr1   = (const float*)d_in[4];
    const float* W_h    = (const float*)d_in[5];
    const float* b_h    = (const float*)d_in[6];
    const float* beta2  = (const float*)d_in[7];
    const float* thr2   = (const float*)d_in[8];
    const float* W_h1   = (const float*)d_in[9];
    const float* b_h1   = (const float*)d_in[10];
    const float* W_f    = (const float*)d_in[11];
    const float* b_f    = (const float*)d_in[12];
    const float* beta_f = (const float*)d_in[13];
    const float* W_a    = (const float*)d_in[14];
    const float* b_a    = (const float*)d_in[15];
    const float* beta_a = (const float*)d_in[16];
    float* out = (float*)d_out;

    float* ws = (float*)d_ws;
    size_t off = 0;
    auto alloc = [&](size_t n) { float* p = ws + off; off += n; return p; };
    float* Wt_in = alloc(257 * 256);
    float* Wt_h  = alloc(257 * 256);
    float* Wt_h1 = alloc(257 * 256);
    float* WtO   = alloc(257 * 128);
    float* m1s   = alloc((size_t)Bsz * Hh);
    float* m2s   = alloc((size_t)Bsz * Hh);
    float* m3s   = alloc((size_t)Bsz * Hh);
    float* mos   = alloc((size_t)Bsz * 128);
    const size_t fixed = off;

    int TC = 1;
    const int cands[8] = {128, 64, 32, 16, 8, 4, 2, 1};
    for (int i = 0; i < 8; ++i) {
        if ((fixed + (size_t)cands[i] * Bsz * Hh) * sizeof(float) <= ws_size) { TC = cands[i]; break; }
    }
    float* cur1 = alloc((size_t)TC * Bsz * Hh);

    pack_t<<<257, 256, 0, stream>>>(W_in, Wt_in, 256, 256);
    pack_t<<<257, 256, 0, stream>>>(W_h,  Wt_h,  256, 256);
    pack_t<<<257, 256, 0, stream>>>(W_h1, Wt_h1, 256, 256);
    pack_o<<<129, 256, 0, stream>>>(W_f, W_a, WtO);

    const int nch = Tt / TC;
    for (int c = 0; c < nch; ++c) {
        const int tg = c * TC;
        if (TC >= 32)
            gemm_l1_r8<32><<<dim3(Bsz, TC / 32), 256, 0, stream>>>(x, Wt_in, b_in, cur1, tg, TC);
        else if (TC == 16)
            gemm_l1_lds<16><<<dim3(Bsz, 1), 256, 0, stream>>>(x, Wt_in, b_in, cur1, tg, TC);
        else if (TC == 8)
            gemm_l1_lds<8><<<dim3(Bsz, 1), 256, 0, stream>>>(x, Wt_in, b_in, cur1, tg, TC);
        else if (TC == 4)
            gemm_l1_simple<4><<<Bsz, 256, 0, stream>>>(x, Wt_in, b_in, cur1, tg);
        else if (TC == 2)
            gemm_l1_simple<2><<<Bsz, 256, 0, stream>>>(x, Wt_in, b_in, cur1, tg);
        else
            gemm_l1_simple<1><<<Bsz, 256, 0, stream>>>(x, Wt_in, b_in, cur1, tg);

        snn_rec<<<Bsz / 4, 256, 0, stream>>>(
            cur1, Wt_h, Wt_h1, WtO,
            beta1, thr1, b_h, beta2, thr2, b_h1,
            b_f, beta_f, b_a, beta_a,
            m1s, m2s, m3s, mos, out, TC, (c == 0) ? 1 : 0);
    }
}